// Round 13
// baseline (366.457 us; speedup 1.0000x reference)
//
#include <hip/hip_runtime.h>
#include <hip/hip_bf16.h>
#include <stdint.h>

#define EPSF 1e-8f

typedef __attribute__((ext_vector_type(8))) short short8;
typedef __attribute__((ext_vector_type(8))) _Float16 half8;
typedef __attribute__((ext_vector_type(16))) float floatx16;

__device__ __forceinline__ unsigned short f2h(float f) {
    _Float16 h = (_Float16)f;
    return __builtin_bit_cast(unsigned short, h);
}
__device__ __forceinline__ float h2f(unsigned short u) {
    return (float)__builtin_bit_cast(_Float16, u);
}

// ---------------- fused conversion kernel (float4-vectorized) ----------------

__global__ void prep_kernel(const float4* __restrict__ x4, ushort4* __restrict__ x16,
                            const float4* __restrict__ wi4, ushort4* __restrict__ wi16,
                            const float4* __restrict__ wo4, ushort4* __restrict__ wo16,
                            int nx4, int nw4, int nwo4) {
    int i = blockIdx.x * blockDim.x + threadIdx.x;
    float4 f; ushort4 u;
    if (i < nx4) {
        f = x4[i];
        u.x = f2h(f.x); u.y = f2h(f.y); u.z = f2h(f.z); u.w = f2h(f.w);
        x16[i] = u;
    } else if (i < nx4 + nw4) {
        int j = i - nx4;
        f = wi4[j];
        u.x = f2h(f.x); u.y = f2h(f.y); u.z = f2h(f.z); u.w = f2h(f.w);
        wi16[j] = u;
    } else if (i < nx4 + nw4 + nwo4) {
        int j = i - nx4 - nw4;
        f = wo4[j];
        u.x = f2h(f.x); u.y = f2h(f.y); u.z = f2h(f.z); u.w = f2h(f.w);
        wo16[j] = u;
    }
}

// ---------------- MFMA GEMM (C = A * B^T + bias), fp16, 32x32x16 ----------------
// XOR-swizzled LDS staging (conflict-free). Wave grid NW_R x NW_C (block =
// NW_R*NW_C*64 threads). Fragment layouts:
//   A/B: m|n = lane&31, k = (lane>>5)*8 + i   (4 VGPRs = 8 fp16)
//   C/D: col = lane&31, row = (reg&3) + 8*(reg>>2) + 4*(lane>>5)  [m74/m101]

__device__ __forceinline__ void gld16(const unsigned short* g, unsigned short* l) {
    __builtin_amdgcn_global_load_lds(
        (const __attribute__((address_space(1))) unsigned int*)g,
        (__attribute__((address_space(3))) unsigned int*)l, 16, 0, 0);
}

template <int BM, int BN, int BK, bool HALFOUT, int NW_R, int NW_C>
__global__ __launch_bounds__(NW_R * NW_C * 64)
void gemm_bt(const unsigned short* __restrict__ Am, const unsigned short* __restrict__ Bm,
             const float* __restrict__ bias, void* __restrict__ Cv,
             int M, int N, int K) {
    constexpr int NT  = NW_R * NW_C * 64;
    constexpr int IF  = BM / (NW_R * 32);
    constexpr int JF  = BN / (NW_C * 32);
    constexpr int KH  = BK / 16;
    constexpr int CPR = BK / 8;        // 16B chunks per row
    extern __shared__ unsigned short smem[];
    unsigned short* sA = smem;
    unsigned short* sB = smem + BM * BK;

    const int tid  = threadIdx.x;
    const int lane = tid & 63;
    const int wid  = tid >> 6;
    const int wr   = wid % NW_R, wc = wid / NW_R;
    const int m32  = lane & 31, half = lane >> 5;

    const int rowA0 = blockIdx.y * BM;
    const int rowB0 = blockIdx.x * BN;

    floatx16 acc[IF][JF];
#pragma unroll
    for (int i = 0; i < IF; i++)
#pragma unroll
        for (int j = 0; j < JF; j++)
#pragma unroll
            for (int r = 0; r < 16; r++) acc[i][j][r] = 0.f;

    const int nk = K / BK;
    for (int kt = 0; kt < nk; ++kt) {
        const int k0 = kt * BK;
#pragma unroll
        for (int i = 0; i < BM * CPR / NT; i++) {
            int c = tid + NT * i;
            int r = c / CPR, ccl = c % CPR;
            int ccg = ccl ^ (r & (CPR - 1));   // swizzled source chunk
            gld16(Am + (size_t)(rowA0 + r) * K + k0 + ccg * 8, sA + c * 8);
        }
#pragma unroll
        for (int i = 0; i < BN * CPR / NT; i++) {
            int c = tid + NT * i;
            int r = c / CPR, ccl = c % CPR;
            int ccg = ccl ^ (r & (CPR - 1));
            gld16(Bm + (size_t)(rowB0 + r) * K + k0 + ccg * 8, sB + c * 8);
        }
        __syncthreads();

#pragma unroll
        for (int kh = 0; kh < KH; kh++) {
            const int kc = kh * 2 + half;      // 16B chunk index of this lane's k
            short8 a[IF], b[JF];
#pragma unroll
            for (int i = 0; i < IF; i++) {
                int ra = wr * (BM / NW_R) + i * 32 + m32;
                int pa = ra * CPR + (kc ^ (ra & (CPR - 1)));
                a[i] = *(const short8*)(sA + pa * 8);
            }
#pragma unroll
            for (int j = 0; j < JF; j++) {
                int rb = wc * (BN / NW_C) + j * 32 + m32;
                int pb = rb * CPR + (kc ^ (rb & (CPR - 1)));
                b[j] = *(const short8*)(sB + pb * 8);
            }
#pragma unroll
            for (int i = 0; i < IF; i++)
#pragma unroll
                for (int j = 0; j < JF; j++)
                    acc[i][j] = __builtin_amdgcn_mfma_f32_32x32x16_f16(
                        __builtin_bit_cast(half8, a[i]), __builtin_bit_cast(half8, b[j]),
                        acc[i][j], 0, 0, 0);
        }
        __syncthreads();
    }

    // C/D: col=lane&31, row=(reg&3)+8*(reg>>2)+4*half  [verified m74/m101]
#pragma unroll
    for (int i = 0; i < IF; i++) {
#pragma unroll
        for (int j = 0; j < JF; j++) {
            int col  = rowB0 + wc * (BN / NW_C) + j * 32 + m32;
            float bv = bias[col];
#pragma unroll
            for (int r = 0; r < 16; r++) {
                int row = rowA0 + wr * (BM / NW_R) + i * 32 + (r & 3) + 8 * (r >> 2) + 4 * half;
                if (HALFOUT)
                    ((unsigned short*)Cv)[(size_t)row * N + col] = f2h(acc[i][j][r] + bv);
                else
                    ((float*)Cv)[(size_t)row * N + col] = acc[i][j][r] + bv;
            }
        }
    }
}

// ---------------- fused quaternion prefix-product scan ----------------
// One kernel: block = 8 h x 32 segments (256 thr), grid (H/8, B).
// Phase 1: per-thread 64-step raw segment product -> LDS.
// 8-thread serial exclusive scan over 32 segments (same op order as before).
// Phase 2: re-read v (96 KB/block, L2-hot), apply prefix, qnorm, write fp16
// states; the scan threads emit m_final.

struct Q { float w, x, y, z; };

__device__ __forceinline__ Q qmul(Q a, Q b) {   // a later (left), b earlier
    Q r;
    r.w = a.w * b.w - a.x * b.x - a.y * b.y - a.z * b.z;
    r.x = a.w * b.x + a.x * b.w + a.y * b.z - a.z * b.y;
    r.y = a.w * b.y - a.x * b.z + a.y * b.w + a.z * b.x;
    r.z = a.w * b.z + a.x * b.y - a.y * b.x + a.z * b.w;
    return r;
}
__device__ __forceinline__ Q qnorm(Q a) {
    float nn = a.w * a.w + a.x * a.x + a.y * a.y + a.z * a.z;
    float inv = __frsqrt_rn(nn);
    Q r; r.w = a.w * inv; r.x = a.x * inv; r.y = a.y * inv; r.z = a.z * inv;
    return r;
}
__device__ __forceinline__ Q vquat(float vx, float vy, float vz) {
    float th = sqrtf(vx * vx + vy * vy + vz * vz);
    float s_, c_;
    __sincosf(th, &s_, &c_);
    float k = __fdividef(s_, th + EPSF);
    Q q; q.w = c_; q.x = k * vx; q.y = k * vy; q.z = k * vz;
    return q;
}

#define SEG  64
#define NSEG 32

__global__ __launch_bounds__(256)
void scan_kernel(const unsigned short* __restrict__ v, unsigned short* __restrict__ st,
                 float* __restrict__ m_final, int S, int H) {
    const int b  = blockIdx.y;
    const int hb = blockIdx.x * 8;
    const int hl = threadIdx.x & 7;
    const int sg = threadIdx.x >> 3;      // 0..31
    const int h  = hb + hl;
    const int s0 = sg * SEG;
    const size_t vstep = (size_t)3 * H;
    const size_t sstep = (size_t)4 * H;
    const unsigned short* vp = v + ((size_t)b * S + s0) * vstep + (size_t)h * 3;
    unsigned short* sp = st + ((size_t)b * S + s0) * sstep + (size_t)h * 4;

    constexpr int CH = 8;
    float ax[CH], ay[CH], az[CH], bx[CH], by[CH], bz[CH];

    // ---- phase 1: raw segment product ----
#pragma unroll
    for (int i = 0; i < CH; ++i) {
        ax[i] = h2f(vp[i * vstep + 0]); ay[i] = h2f(vp[i * vstep + 1]); az[i] = h2f(vp[i * vstep + 2]);
    }
    Q c = {1.f, 0.f, 0.f, 0.f};
    const int NC = SEG / CH;  // 8 chunks
    for (int cc = 0; cc < NC; cc += 2) {
        if (cc + 1 < NC) {
            const unsigned short* p = vp + (size_t)(cc + 1) * CH * vstep;
#pragma unroll
            for (int i = 0; i < CH; ++i) {
                bx[i] = h2f(p[i * vstep + 0]); by[i] = h2f(p[i * vstep + 1]); bz[i] = h2f(p[i * vstep + 2]);
            }
        }
#pragma unroll
        for (int i = 0; i < CH; ++i) c = qmul(vquat(ax[i], ay[i], az[i]), c);
        if (cc + 2 < NC) {
            const unsigned short* p = vp + (size_t)(cc + 2) * CH * vstep;
#pragma unroll
            for (int i = 0; i < CH; ++i) {
                ax[i] = h2f(p[i * vstep + 0]); ay[i] = h2f(p[i * vstep + 1]); az[i] = h2f(p[i * vstep + 2]);
            }
        }
#pragma unroll
        for (int i = 0; i < CH; ++i) c = qmul(vquat(bx[i], by[i], bz[i]), c);
    }

    __shared__ float4 prods[NSEG][8];
    prods[sg][hl] = make_float4(c.w, c.x, c.y, c.z);
    __syncthreads();

    // ---- exclusive scan (8 threads, one per h; same op order as before) ----
    if (threadIdx.x < 8) {
        Q r = {1.f, 0.f, 0.f, 0.f};
        for (int s2 = 0; s2 < NSEG; ++s2) {
            float4 pv = prods[s2][threadIdx.x];
            prods[s2][threadIdx.x] = make_float4(r.w, r.x, r.y, r.z);
            Q pq = {pv.x, pv.y, pv.z, pv.w};
            r = qmul(pq, r);
        }
        Q m = qnorm(r);
        float* mf = m_final + ((size_t)b * H + hb + threadIdx.x) * 4;
        mf[0] = m.w; mf[1] = m.x; mf[2] = m.y; mf[3] = m.z;
    }
    __syncthreads();

    float4 e = prods[sg][hl];
    Q R = {e.x, e.y, e.z, e.w};

    // ---- phase 2: apply prefix, write states ----
#pragma unroll
    for (int i = 0; i < CH; ++i) {
        ax[i] = h2f(vp[i * vstep + 0]); ay[i] = h2f(vp[i * vstep + 1]); az[i] = h2f(vp[i * vstep + 2]);
    }
    for (int cc = 0; cc < NC; cc += 2) {
        if (cc + 1 < NC) {
            const unsigned short* pp = vp + (size_t)(cc + 1) * CH * vstep;
#pragma unroll
            for (int i = 0; i < CH; ++i) {
                bx[i] = h2f(pp[i * vstep + 0]); by[i] = h2f(pp[i * vstep + 1]); bz[i] = h2f(pp[i * vstep + 2]);
            }
        }
#pragma unroll
        for (int i = 0; i < CH; ++i) {
            R = qmul(vquat(ax[i], ay[i], az[i]), R);
            Q m = qnorm(R);
            ushort4 u; u.x = f2h(m.w); u.y = f2h(m.x); u.z = f2h(m.y); u.w = f2h(m.z);
            *(ushort4*)(sp + (size_t)(cc * CH + i) * sstep) = u;
        }
        if (cc + 2 < NC) {
            const unsigned short* pp = vp + (size_t)(cc + 2) * CH * vstep;
#pragma unroll
            for (int i = 0; i < CH; ++i) {
                ax[i] = h2f(pp[i * vstep + 0]); ay[i] = h2f(pp[i * vstep + 1]); az[i] = h2f(pp[i * vstep + 2]);
            }
        }
#pragma unroll
        for (int i = 0; i < CH; ++i) {
            R = qmul(vquat(bx[i], by[i], bz[i]), R);
            Q m = qnorm(R);
            ushort4 u; u.x = f2h(m.w); u.y = f2h(m.x); u.z = f2h(m.y); u.w = f2h(m.z);
            *(ushort4*)(sp + (size_t)((cc + 1) * CH + i) * sstep) = u;
        }
    }
}

// ---------------- launch ----------------

extern "C" void kernel_launch(void* const* d_in, const int* in_sizes, int n_in,
                              void* d_out, int out_size, void* d_ws, size_t ws_size,
                              hipStream_t stream) {
    const float* x     = (const float*)d_in[0];
    const float* W_in  = (const float*)d_in[1];
    const float* b_in  = (const float*)d_in[2];
    const float* W_out = (const float*)d_in[3];
    const float* b_out = (const float*)d_in[4];
    float* out = (float*)d_out;

    const int B = 4, S = 2048, D = 1024, H = 1024;
    const int M  = B * S;    // 8192
    const int N1 = 3 * H;    // 3072
    const int K1 = D;        // 1024
    const int N2 = D;        // 1024
    const int K2 = 4 * H;    // 4096

    // ws layout (bytes):
    //   [0, 50331648)            v     fp16 M*N1 (48 MB)
    //   [50331648, 117440512)    st    fp16 M*K2 (64 MB); x16/wi16 overlap
    //   [117440512, 125829120)   wo16  fp16 N2*K2 (8 MB)
    char* ws = (char*)d_ws;
    unsigned short* v    = (unsigned short*)(ws);
    unsigned short* st   = (unsigned short*)(ws + 50331648u);
    unsigned short* x16  = (unsigned short*)(ws + 50331648u);
    unsigned short* wi16 = (unsigned short*)(ws + 50331648u + 16777216u);
    unsigned short* wo16 = (unsigned short*)(ws + 117440512u);

    const int nx  = M * K1;    // 8388608
    const int nw  = N1 * K1;   // 3145728
    const int nwo = N2 * K2;   // 4194304
    const int n4  = (nx + nw + nwo) / 4;

    prep_kernel<<<(n4 + 255) / 256, 256, 0, stream>>>(
        (const float4*)x, (ushort4*)x16, (const float4*)W_in, (ushort4*)wi16,
        (const float4*)W_out, (ushort4*)wo16, nx / 4, nw / 4, nwo / 4);

    // v = x @ W_in^T + b_in   (fp16 out; 128x128 BK=64, 2x2 waves/256 thr)
    gemm_bt<128, 128, 64, true, 2, 2><<<dim3(N1 / 128, M / 128), 256, 32768, stream>>>(
        x16, wi16, b_in, v, M, N1, K1);

    // fused hierarchical scan (single kernel)
    scan_kernel<<<dim3(H / 8, B), 256, 0, stream>>>(v, st, out + (size_t)M * D, S, H);

    // out = states @ W_out^T + b_out
    // 128x256 tile, 512 thr (4x2 waves, acc=64 VGPR/wave): A-refetch demand
    // 512->256 MB; concurrency unchanged at 8 waves/CU.
    gemm_bt<128, 256, 64, false, 4, 2><<<dim3(N2 / 256, M / 128), 512, 49152, stream>>>(
        st, wo16, b_out, out, M, N2, K2);
}